// Round 1
// baseline (455.952 us; speedup 1.0000x reference)
//
#include <hip/hip_runtime.h>
#include <hip/hip_bf16.h>
#include <cstdint>
#include <cstddef>

// GCN 2-layer forward for MI355X (gfx950).
// Pipeline per call (deterministic work, all on `stream`):
//   1. in-degree histogram (int atomics)          -> cnt[N]
//   2. dinv[i] = rsqrt(cnt[i]+1)  (self-loop)     -> dinv[N]
//   3. exclusive scan of cnt                      -> rowptr[N+1]
//   4. CSR fill (src ids bucketed by dst)         -> col[E]
//   5. h  = x @ W1          (fp32 tiled GEMM)
//   6. h1 = relu(Agg(h) + b1)   one wave/node, float4 lanes
//   7. g  = h1 @ W2
//   8. out= relu(Agg(g) + b2)   one wave/node, float2 lanes
// Agg(h)[i] = dinv[i] * ( dinv[i]*h[i] + sum_{e: dst=i} dinv[src_e]*h[src_e] )

#define WAVE 64

__global__ __launch_bounds__(256) void k_fill_i32(int* __restrict__ p, int v, int n) {
    int i = blockIdx.x * 256 + threadIdx.x;
    if (i < n) p[i] = v;
}

__global__ __launch_bounds__(256) void k_count(const int* __restrict__ dst,
                                               int* __restrict__ cnt, int E) {
    int e = blockIdx.x * 256 + threadIdx.x;
    if (e < E) atomicAdd(&cnt[dst[e]], 1);
}

__global__ __launch_bounds__(256) void k_dinv(const int* __restrict__ cnt,
                                              float* __restrict__ dinv, int n) {
    int i = blockIdx.x * 256 + threadIdx.x;
    if (i < n) dinv[i] = rsqrtf((float)(cnt[i] + 1));
}

// --- exclusive scan of cnt[N] -> rowptr[N], rowptr[N]=E, 3 kernels ---
__global__ __launch_bounds__(256) void k_scan_block(const int* __restrict__ cnt,
                                                    int* __restrict__ rowptr,
                                                    int* __restrict__ partial, int n) {
    __shared__ int s[256];
    int i = blockIdx.x * 256 + threadIdx.x;
    int v = (i < n) ? cnt[i] : 0;
    s[threadIdx.x] = v;
    __syncthreads();
    for (int off = 1; off < 256; off <<= 1) {
        int t = (threadIdx.x >= off) ? s[threadIdx.x - off] : 0;
        __syncthreads();
        s[threadIdx.x] += t;
        __syncthreads();
    }
    if (i < n) rowptr[i] = s[threadIdx.x] - v;  // exclusive
    if (threadIdx.x == 255) partial[blockIdx.x] = s[255];
}

__global__ __launch_bounds__(256) void k_scan_partial(int* __restrict__ partial, int nb) {
    // nb <= 256 (N=50000 -> nb=196)
    __shared__ int s[256];
    int v = (threadIdx.x < nb) ? partial[threadIdx.x] : 0;
    s[threadIdx.x] = v;
    __syncthreads();
    for (int off = 1; off < 256; off <<= 1) {
        int t = (threadIdx.x >= off) ? s[threadIdx.x - off] : 0;
        __syncthreads();
        s[threadIdx.x] += t;
        __syncthreads();
    }
    if (threadIdx.x < nb) partial[threadIdx.x] = s[threadIdx.x] - v;  // exclusive
}

__global__ __launch_bounds__(256) void k_scan_add(int* __restrict__ rowptr,
                                                  const int* __restrict__ partial,
                                                  int n, int e) {
    int i = blockIdx.x * 256 + threadIdx.x;
    if (i < n) rowptr[i] += partial[blockIdx.x];
    if (i == 0) rowptr[n] = e;  // total = E
}

__global__ __launch_bounds__(256) void k_fill_col(const int* __restrict__ src,
                                                  const int* __restrict__ dst,
                                                  const int* __restrict__ rowptr,
                                                  int* __restrict__ cur,
                                                  int* __restrict__ colv, int E) {
    int e = blockIdx.x * 256 + threadIdx.x;
    if (e < E) {
        int d = dst[e];
        int p = rowptr[d] + atomicAdd(&cur[d], 1);
        colv[p] = src[e];
    }
}

// --- fp32 tiled GEMM: C[M,Nc] = A[M,K] @ B[K,Nc]; Nc%64==0, K%16==0 ---
__global__ __launch_bounds__(256) void k_gemm(const float* __restrict__ A,
                                              const float* __restrict__ B,
                                              float* __restrict__ C,
                                              int M, int K, int Nc) {
    __shared__ float As[64][20];  // pad 20: 80B row stride, 16B-aligned-safe (scalar writes anyway)
    __shared__ float Bs[16][68];  // pad 68: 272B stride, float4-write aligned, 2-way max read conflict
    const int m0 = blockIdx.x * 64, n0 = blockIdx.y * 64;
    const int tid = threadIdx.x;
    const int ty = tid >> 4, tx = tid & 15;
    const int ar = tid >> 2, ac4 = (tid & 3) * 4;
    const int br = tid >> 4, bc4 = (tid & 15) * 4;

    float acc[4][4] = {};

    for (int k0 = 0; k0 < K; k0 += 16) {
        float4 av = make_float4(0.f, 0.f, 0.f, 0.f);
        if (m0 + ar < M)
            av = *(const float4*)(A + (size_t)(m0 + ar) * K + k0 + ac4);
        As[ar][ac4 + 0] = av.x;
        As[ar][ac4 + 1] = av.y;
        As[ar][ac4 + 2] = av.z;
        As[ar][ac4 + 3] = av.w;
        float4 bv = *(const float4*)(B + (size_t)(k0 + br) * Nc + n0 + bc4);
        *(float4*)&Bs[br][bc4] = bv;
        __syncthreads();
#pragma unroll
        for (int k = 0; k < 16; ++k) {
            float a[4], b[4];
#pragma unroll
            for (int i = 0; i < 4; ++i) a[i] = As[ty * 4 + i][k];
#pragma unroll
            for (int j = 0; j < 4; ++j) b[j] = Bs[k][tx * 4 + j];
#pragma unroll
            for (int i = 0; i < 4; ++i)
#pragma unroll
                for (int j = 0; j < 4; ++j) acc[i][j] += a[i] * b[j];
        }
        __syncthreads();
    }
#pragma unroll
    for (int i = 0; i < 4; ++i) {
        int r = m0 + ty * 4 + i;
        if (r < M) {
            float4 v = make_float4(acc[i][0], acc[i][1], acc[i][2], acc[i][3]);
            *(float4*)(C + (size_t)r * Nc + n0 + tx * 4) = v;
        }
    }
}

// --- aggregation: one wave per node; FPL floats per lane (F = FPL*64) ---
template <int FPL>
__global__ __launch_bounds__(256) void k_aggregate(const float* __restrict__ h,
                                                   const int* __restrict__ rowptr,
                                                   const int* __restrict__ colv,
                                                   const float* __restrict__ dinv,
                                                   const float* __restrict__ bias,
                                                   float* __restrict__ out, int n) {
    const int F = FPL * WAVE;
    int wid = blockIdx.x * (256 / WAVE) + (threadIdx.x >> 6);
    if (wid >= n) return;
    int lane = threadIdx.x & 63;

    float acc[FPL];
    float di = dinv[wid];
    {
        const float* hr = h + (size_t)wid * F + lane * FPL;
        if constexpr (FPL == 4) {
            float4 v = *(const float4*)hr;
            acc[0] = di * v.x; acc[1] = di * v.y; acc[2] = di * v.z; acc[3] = di * v.w;
        } else {
            float2 v = *(const float2*)hr;
            acc[0] = di * v.x; acc[1] = di * v.y;
        }
    }
    int p0 = rowptr[wid], p1 = rowptr[wid + 1];  // wave-uniform
    for (int p = p0; p < p1; ++p) {
        int s = colv[p];
        float ds = dinv[s];
        const float* hs = h + (size_t)s * F + lane * FPL;
        if constexpr (FPL == 4) {
            float4 v = *(const float4*)hs;
            acc[0] += ds * v.x; acc[1] += ds * v.y; acc[2] += ds * v.z; acc[3] += ds * v.w;
        } else {
            float2 v = *(const float2*)hs;
            acc[0] += ds * v.x; acc[1] += ds * v.y;
        }
    }
    float* o = out + (size_t)wid * F + lane * FPL;
#pragma unroll
    for (int j = 0; j < FPL; ++j) {
        float v = di * acc[j] + bias[lane * FPL + j];
        o[j] = v > 0.f ? v : 0.f;
    }
}

extern "C" void kernel_launch(void* const* d_in, const int* in_sizes, int n_in,
                              void* d_out, int out_size, void* d_ws, size_t ws_size,
                              hipStream_t stream) {
    const float* x  = (const float*)d_in[0];
    const int*   ei = (const int*)d_in[1];   // [2, E] int32: row0=src, row1=dst
    const float* W1 = (const float*)d_in[2];
    const float* b1 = (const float*)d_in[3];
    const float* W2 = (const float*)d_in[4];
    const float* b2 = (const float*)d_in[5];

    const int HID = in_sizes[3];             // 256
    const int IN  = in_sizes[2] / HID;       // 256
    const int OUT = in_sizes[5];             // 128
    const int N   = in_sizes[0] / IN;        // 50000
    const int E   = in_sizes[1] / 2;         // 800000

    const int* src = ei;
    const int* dst = ei + E;

    // workspace carve-out (~106 MB total)
    char* wsb = (char*)d_ws;
    size_t off = 0;
    auto carve = [&](size_t bytes) -> char* {
        char* p = wsb + off;
        off += (bytes + 255) & ~(size_t)255;
        return p;
    };
    float* h      = (float*)carve((size_t)N * HID * 4);
    float* h1     = (float*)carve((size_t)N * HID * 4);
    float* dinv   = (float*)carve((size_t)N * 4);
    int*   rowptr = (int*)carve((size_t)(N + 1) * 4);
    int*   cnt    = (int*)carve((size_t)N * 4);
    int*   part   = (int*)carve(1024);
    int*   colv   = (int*)carve((size_t)E * 4);
    float* g      = h;  // layer-2 GEMM output reuses h (h dead after aggregate1)
    (void)ws_size; (void)n_in; (void)out_size;

    const int nbN = (N + 255) / 256;   // 196 (<=256, required by k_scan_partial)
    const int nbE = (E + 255) / 256;

    k_fill_i32<<<nbN, 256, 0, stream>>>(cnt, 0, N);
    k_count<<<nbE, 256, 0, stream>>>(dst, cnt, E);
    k_dinv<<<nbN, 256, 0, stream>>>(cnt, dinv, N);
    k_scan_block<<<nbN, 256, 0, stream>>>(cnt, rowptr, part, N);
    k_scan_partial<<<1, 256, 0, stream>>>(part, nbN);
    k_scan_add<<<nbN, 256, 0, stream>>>(rowptr, part, N, E);
    k_fill_i32<<<nbN, 256, 0, stream>>>(cnt, 0, N);  // reuse as cursor
    k_fill_col<<<nbE, 256, 0, stream>>>(src, dst, rowptr, cnt, colv, E);

    k_gemm<<<dim3((N + 63) / 64, HID / 64), 256, 0, stream>>>(x, W1, h, N, IN, HID);
    k_aggregate<4><<<(N + 3) / 4, 256, 0, stream>>>(h, rowptr, colv, dinv, b1, h1, N);
    k_gemm<<<dim3((N + 63) / 64, OUT / 64), 256, 0, stream>>>(h1, W2, g, N, HID, OUT);
    k_aggregate<2><<<(N + 3) / 4, 256, 0, stream>>>(g, rowptr, colv, dinv, b2, (float*)d_out, N);
}

// Round 2
// 269.108 us; speedup vs baseline: 1.6943x; 1.6943x over previous
//
#include <hip/hip_runtime.h>
#include <hip/hip_bf16.h>
#include <cstdint>
#include <cstddef>

// GCN 2-layer forward, MI355X (gfx950).
//   CSR build (unchanged) -> dinv
//   W1,W2 transposed on device once per call (k-contiguous GEMM B staging)
//   hs = bf16( dinv[m] * (x @ W1) )        split-bf16 MFMA GEMM (3-term)
//   h1 = relu( dinv[i]*(sum rows hs) + b1 )  fp32, row-sum gather (bf16 payload)
//   gs = bf16( dinv[m] * (h1 @ W2) )
//   out= relu( dinv[i]*(sum rows gs) + b2 )

#define WAVE 64

typedef short bf16x8 __attribute__((ext_vector_type(8)));
typedef float f32x4 __attribute__((ext_vector_type(4)));

__device__ __forceinline__ float b2f(unsigned short u) {
    union { unsigned int i; float f; } c; c.i = ((unsigned int)u) << 16; return c.f;
}
__device__ __forceinline__ unsigned short f2b(float f) {
    union { float f; unsigned int i; } c; c.f = f;
    return (unsigned short)((c.i + 0x7FFFu + ((c.i >> 16) & 1u)) >> 16);
}
// Dekker-style split: f = b2f(hi) + lo_f, hi = truncation (exact residual), lo = RN.
__device__ __forceinline__ void split2(float f, unsigned short& hi, unsigned short& lo) {
    union { float f; unsigned int i; } c; c.f = f;
    hi = (unsigned short)(c.i >> 16);
    union { unsigned int i; float f; } h; h.i = c.i & 0xFFFF0000u;
    lo = f2b(f - h.f);
}

// ---------------- CSR build ----------------
__global__ __launch_bounds__(256) void k_fill_i32(int* __restrict__ p, int v, int n) {
    int i = blockIdx.x * 256 + threadIdx.x;
    if (i < n) p[i] = v;
}

__global__ __launch_bounds__(256) void k_count(const int* __restrict__ dst,
                                               int* __restrict__ cnt, int E) {
    int e = blockIdx.x * 256 + threadIdx.x;
    if (e < E) atomicAdd(&cnt[dst[e]], 1);
}

__global__ __launch_bounds__(256) void k_dinv(const int* __restrict__ cnt,
                                              float* __restrict__ dinv, int n) {
    int i = blockIdx.x * 256 + threadIdx.x;
    if (i < n) dinv[i] = rsqrtf((float)(cnt[i] + 1));
}

__global__ __launch_bounds__(256) void k_scan_block(const int* __restrict__ cnt,
                                                    int* __restrict__ rowptr,
                                                    int* __restrict__ partial, int n) {
    __shared__ int s[256];
    int i = blockIdx.x * 256 + threadIdx.x;
    int v = (i < n) ? cnt[i] : 0;
    s[threadIdx.x] = v;
    __syncthreads();
    for (int off = 1; off < 256; off <<= 1) {
        int t = (threadIdx.x >= off) ? s[threadIdx.x - off] : 0;
        __syncthreads();
        s[threadIdx.x] += t;
        __syncthreads();
    }
    if (i < n) rowptr[i] = s[threadIdx.x] - v;
    if (threadIdx.x == 255) partial[blockIdx.x] = s[255];
}

__global__ __launch_bounds__(256) void k_scan_partial(int* __restrict__ partial, int nb) {
    __shared__ int s[256];
    int v = (threadIdx.x < nb) ? partial[threadIdx.x] : 0;
    s[threadIdx.x] = v;
    __syncthreads();
    for (int off = 1; off < 256; off <<= 1) {
        int t = (threadIdx.x >= off) ? s[threadIdx.x - off] : 0;
        __syncthreads();
        s[threadIdx.x] += t;
        __syncthreads();
    }
    if (threadIdx.x < nb) partial[threadIdx.x] = s[threadIdx.x] - v;
}

__global__ __launch_bounds__(256) void k_scan_add(int* __restrict__ rowptr,
                                                  const int* __restrict__ partial,
                                                  int n, int e) {
    int i = blockIdx.x * 256 + threadIdx.x;
    if (i < n) rowptr[i] += partial[blockIdx.x];
    if (i == 0) rowptr[n] = e;
}

__global__ __launch_bounds__(256) void k_fill_col(const int* __restrict__ src,
                                                  const int* __restrict__ dst,
                                                  const int* __restrict__ rowptr,
                                                  int* __restrict__ cur,
                                                  int* __restrict__ colv, int E) {
    int e = blockIdx.x * 256 + threadIdx.x;
    if (e < E) {
        int d = dst[e];
        int p = rowptr[d] + atomicAdd(&cur[d], 1);
        colv[p] = src[e];
    }
}

// ---------------- transpose (R,C multiples of 64): dst[C][R] = src[R][C]^T ----
__global__ __launch_bounds__(256) void k_transpose(const float* __restrict__ src,
                                                   float* __restrict__ dst,
                                                   int R, int C) {
    __shared__ float tile[64][65];
    int r0 = blockIdx.y * 64, c0 = blockIdx.x * 64;
    for (int i = threadIdx.x; i < 64 * 64; i += 256) {
        int r = i >> 6, c = i & 63;
        tile[r][c] = src[(size_t)(r0 + r) * C + c0 + c];
    }
    __syncthreads();
    for (int i = threadIdx.x; i < 64 * 64; i += 256) {
        int r = i >> 6, c = i & 63;
        dst[(size_t)(c0 + r) * R + r0 + c] = tile[c][r];
    }
}

// ---------------- split-bf16 MFMA GEMM ----------------
// C[m][n] = bf16( scale[m] * (A[M][K] @ BT[Nc][K]^T) ), 3-MFMA split per fragment.
// Requires K%32==0, Nc%128==0. Block 256 thr = 4 waves (2x2 of 64x64), tile 128x128, BK=32.
__global__ __launch_bounds__(256) void k_gemm_mfma(const float* __restrict__ A,
                                                   const float* __restrict__ BT,
                                                   const float* __restrict__ scale,
                                                   unsigned short* __restrict__ C,
                                                   int M, int K, int Nc) {
    __shared__ __align__(16) unsigned short Ah[128][40];  // pad 40: 80B stride, 2-way max
    __shared__ __align__(16) unsigned short Al[128][40];
    __shared__ __align__(16) unsigned short Bh[128][40];
    __shared__ __align__(16) unsigned short Bl[128][40];

    const int tid = threadIdx.x;
    const int m0 = blockIdx.x * 128, n0 = blockIdx.y * 128;
    const int srow = tid >> 1;           // staging row 0..127
    const int skc  = (tid & 1) * 16;     // staging k offset 0/16
    const int w = tid >> 6, lane = tid & 63;
    const int wr = w >> 1, wc = w & 1;   // wave -> 64x64 sub-tile
    const int fr = lane & 15, kg = lane >> 4;

    f32x4 acc[4][4] = {};

    for (int k0 = 0; k0 < K; k0 += 32) {
        {   // stage A (fp32 -> hi/lo bf16)
            float4 v[4];
            const int arow = m0 + srow;
            if (arow < M) {
                const float* ap = A + (size_t)arow * K + k0 + skc;
#pragma unroll
                for (int i = 0; i < 4; ++i) v[i] = *(const float4*)(ap + i * 4);
            } else {
#pragma unroll
                for (int i = 0; i < 4; ++i) v[i] = make_float4(0.f, 0.f, 0.f, 0.f);
            }
#pragma unroll
            for (int i = 0; i < 4; ++i) {
                ushort4 hv, lv;
                split2(v[i].x, hv.x, lv.x); split2(v[i].y, hv.y, lv.y);
                split2(v[i].z, hv.z, lv.z); split2(v[i].w, hv.w, lv.w);
                *(ushort4*)&Ah[srow][skc + i * 4] = hv;
                *(ushort4*)&Al[srow][skc + i * 4] = lv;
            }
            // stage B (BT is [Nc][K], k-contiguous)
            const float* bp = BT + (size_t)(n0 + srow) * K + k0 + skc;
#pragma unroll
            for (int i = 0; i < 4; ++i) v[i] = *(const float4*)(bp + i * 4);
#pragma unroll
            for (int i = 0; i < 4; ++i) {
                ushort4 hv, lv;
                split2(v[i].x, hv.x, lv.x); split2(v[i].y, hv.y, lv.y);
                split2(v[i].z, hv.z, lv.z); split2(v[i].w, hv.w, lv.w);
                *(ushort4*)&Bh[srow][skc + i * 4] = hv;
                *(ushort4*)&Bl[srow][skc + i * 4] = lv;
            }
        }
        __syncthreads();
        bf16x8 ah[4], al[4], bh[4], bl[4];
#pragma unroll
        for (int i = 0; i < 4; ++i) {
            const int ar = wr * 64 + i * 16 + fr;
            ah[i] = *(const bf16x8*)&Ah[ar][kg * 8];
            al[i] = *(const bf16x8*)&Al[ar][kg * 8];
            const int br = wc * 64 + i * 16 + fr;
            bh[i] = *(const bf16x8*)&Bh[br][kg * 8];
            bl[i] = *(const bf16x8*)&Bl[br][kg * 8];
        }
#pragma unroll
        for (int i = 0; i < 4; ++i)
#pragma unroll
            for (int j = 0; j < 4; ++j) {
                acc[i][j] = __builtin_amdgcn_mfma_f32_16x16x32_bf16(ah[i], bh[j], acc[i][j], 0, 0, 0);
                acc[i][j] = __builtin_amdgcn_mfma_f32_16x16x32_bf16(al[i], bh[j], acc[i][j], 0, 0, 0);
                acc[i][j] = __builtin_amdgcn_mfma_f32_16x16x32_bf16(ah[i], bl[j], acc[i][j], 0, 0, 0);
            }
        __syncthreads();
    }
    // epilogue: C/D layout col=lane&15, row=(lane>>4)*4+reg (m89/m91)
#pragma unroll
    for (int i = 0; i < 4; ++i) {
        const int rbase = m0 + wr * 64 + i * 16 + (lane >> 4) * 4;
#pragma unroll
        for (int r = 0; r < 4; ++r) {
            const int row = rbase + r;
            if (row < M) {
                const float s = scale[row];
#pragma unroll
                for (int j = 0; j < 4; ++j) {
                    const int col = n0 + wc * 64 + j * 16 + fr;
                    C[(size_t)row * Nc + col] = f2b(acc[i][j][r] * s);
                }
            }
        }
    }
}

// ---------------- aggregation: row-sum gather over pre-scaled bf16 rows ------
// out[i][f] = relu( dinv[i] * ( hs[i][f] + sum_{e: dst=i} hs[colv[e]][f] ) + bias[f] )
template <int EPL>
__global__ __launch_bounds__(256) void k_agg(const unsigned short* __restrict__ hs,
                                             const int* __restrict__ rowptr,
                                             const int* __restrict__ colv,
                                             const float* __restrict__ dinv,
                                             const float* __restrict__ bias,
                                             float* __restrict__ out, int n) {
    const int F = EPL * WAVE;
    const int wid = blockIdx.x * 4 + (threadIdx.x >> 6);
    if (wid >= n) return;
    const int lane = threadIdx.x & 63;
    const unsigned short* base = hs + lane * EPL;

    float acc[EPL];
    {   // self row (already scaled by dinv[wid] in GEMM epilogue)
        const unsigned short* p = base + (size_t)wid * F;
        if constexpr (EPL == 4) {
            ushort4 v = *(const ushort4*)p;
            acc[0] = b2f(v.x); acc[1] = b2f(v.y); acc[2] = b2f(v.z); acc[3] = b2f(v.w);
        } else {
            ushort2 v = *(const ushort2*)p;
            acc[0] = b2f(v.x); acc[1] = b2f(v.y);
        }
    }
    const int p0 = rowptr[wid], p1 = rowptr[wid + 1];
    int p = p0;
    for (; p + 4 <= p1; p += 4) {  // 4 outstanding row-gathers
        int s0 = colv[p], s1 = colv[p + 1], s2 = colv[p + 2], s3 = colv[p + 3];
        if constexpr (EPL == 4) {
            ushort4 v0 = *(const ushort4*)(base + (size_t)s0 * F);
            ushort4 v1 = *(const ushort4*)(base + (size_t)s1 * F);
            ushort4 v2 = *(const ushort4*)(base + (size_t)s2 * F);
            ushort4 v3 = *(const ushort4*)(base + (size_t)s3 * F);
            acc[0] += (b2f(v0.x) + b2f(v1.x)) + (b2f(v2.x) + b2f(v3.x));
            acc[1] += (b2f(v0.y) + b2f(v1.y)) + (b2f(v2.y) + b2f(v3.y));
            acc[2] += (b2f(v0.z) + b2f(v1.z)) + (b2f(v2.z) + b2f(v3.z));
            acc[3] += (b2f(v0.w) + b2f(v1.w)) + (b2f(v2.w) + b2f(v3.w));
        } else {
            ushort2 v0 = *(const ushort2*)(base + (size_t)s0 * F);
            ushort2 v1 = *(const ushort2*)(base + (size_t)s1 * F);
            ushort2 v2 = *(const ushort2*)(base + (size_t)s2 * F);
            ushort2 v3 = *(const ushort2*)(base + (size_t)s3 * F);
            acc[0] += (b2f(v0.x) + b2f(v1.x)) + (b2f(v2.x) + b2f(v3.x));
            acc[1] += (b2f(v0.y) + b2f(v1.y)) + (b2f(v2.y) + b2f(v3.y));
        }
    }
    for (; p < p1; ++p) {
        int s = colv[p];
        const unsigned short* q = base + (size_t)s * F;
        if constexpr (EPL == 4) {
            ushort4 v = *(const ushort4*)q;
            acc[0] += b2f(v.x); acc[1] += b2f(v.y); acc[2] += b2f(v.z); acc[3] += b2f(v.w);
        } else {
            ushort2 v = *(const ushort2*)q;
            acc[0] += b2f(v.x); acc[1] += b2f(v.y);
        }
    }
    const float di = dinv[wid];
    float* o = out + (size_t)wid * F + lane * EPL;
#pragma unroll
    for (int j = 0; j < EPL; ++j) {
        float v = di * acc[j] + bias[lane * EPL + j];
        o[j] = v > 0.f ? v : 0.f;
    }
}

extern "C" void kernel_launch(void* const* d_in, const int* in_sizes, int n_in,
                              void* d_out, int out_size, void* d_ws, size_t ws_size,
                              hipStream_t stream) {
    const float* x  = (const float*)d_in[0];
    const int*   ei = (const int*)d_in[1];
    const float* W1 = (const float*)d_in[2];
    const float* b1 = (const float*)d_in[3];
    const float* W2 = (const float*)d_in[4];
    const float* b2 = (const float*)d_in[5];

    const int HID = in_sizes[3];            // 256
    const int IN  = in_sizes[2] / HID;      // 256
    const int OUT = in_sizes[5];            // 128
    const int N   = in_sizes[0] / IN;       // 50000
    const int E   = in_sizes[1] / 2;        // 800000

    const int* src = ei;
    const int* dst = ei + E;

    char* wsb = (char*)d_ws;
    size_t off = 0;
    auto carve = [&](size_t bytes) -> char* {
        char* p = wsb + off;
        off += (bytes + 255) & ~(size_t)255;
        return p;
    };
    unsigned short* hsb = (unsigned short*)carve((size_t)N * HID * 2);  // bf16 scaled h
    float* h1           = (float*)carve((size_t)N * HID * 4);
    unsigned short* gsb = (unsigned short*)carve((size_t)N * OUT * 2);  // bf16 scaled g
    float* dinv   = (float*)carve((size_t)N * 4);
    int*   rowptr = (int*)carve((size_t)(N + 1) * 4);
    int*   cnt    = (int*)carve((size_t)N * 4);
    int*   part   = (int*)carve(1024);
    int*   colv   = (int*)carve((size_t)E * 4);
    float* W1T    = (float*)carve((size_t)IN * HID * 4);
    float* W2T    = (float*)carve((size_t)HID * OUT * 4);
    (void)ws_size; (void)n_in; (void)out_size;

    const int nbN = (N + 255) / 256;   // 196 (<=256 required by k_scan_partial)
    const int nbE = (E + 255) / 256;

    // CSR + dinv
    k_fill_i32<<<nbN, 256, 0, stream>>>(cnt, 0, N);
    k_count<<<nbE, 256, 0, stream>>>(dst, cnt, E);
    k_dinv<<<nbN, 256, 0, stream>>>(cnt, dinv, N);
    k_scan_block<<<nbN, 256, 0, stream>>>(cnt, rowptr, part, N);
    k_scan_partial<<<1, 256, 0, stream>>>(part, nbN);
    k_scan_add<<<nbN, 256, 0, stream>>>(rowptr, part, N, E);
    k_fill_i32<<<nbN, 256, 0, stream>>>(cnt, 0, N);
    k_fill_col<<<nbE, 256, 0, stream>>>(src, dst, rowptr, cnt, colv, E);

    // weight transposes: W1T[HID][IN], W2T[OUT][HID]
    k_transpose<<<dim3(HID / 64, IN / 64), 256, 0, stream>>>(W1, W1T, IN, HID);
    k_transpose<<<dim3(OUT / 64, HID / 64), 256, 0, stream>>>(W2, W2T, HID, OUT);

    // layer 1
    k_gemm_mfma<<<dim3((N + 127) / 128, HID / 128), 256, 0, stream>>>(x, W1T, dinv, hsb, N, IN, HID);
    k_agg<4><<<(N + 3) / 4, 256, 0, stream>>>(hsb, rowptr, colv, dinv, b1, h1, N);
    // layer 2
    k_gemm_mfma<<<dim3((N + 127) / 128, OUT / 128), 256, 0, stream>>>(h1, W2T, dinv, gsb, N, HID, OUT);
    k_agg<2><<<(N + 3) / 4, 256, 0, stream>>>(gsb, rowptr, colv, dinv, b2, (float*)d_out, N);
}